// Round 10
// baseline (589.165 us; speedup 1.0000x reference)
//
#include <hip/hip_runtime.h>
#include <math.h>

#define NN 50000
#define EE 800000
#define HH 256
#define CC 64
#define NPAD 50048          // NN rounded to 128
#define NB 196              // scan blocks = ceil(NN/256)
#define QSCALE 0.09016843798f   // (1/16) * log2(e): folds 1/sqrt(H) and exp->exp2

typedef _Float16 f16x8 __attribute__((ext_vector_type(8)));
typedef _Float16 h2 __attribute__((ext_vector_type(2)));
typedef float f32x4 __attribute__((ext_vector_type(4)));

// exact tanh-gelu via sigmoid identity: 0.5x(1+tanh(z)) = x / (1 + exp(-2z))
__device__ __forceinline__ float gelu_f(float x) {
    const float A = 2.302118074f;    // 2*log2(e)*sqrt(2/pi)
    const float B = 0.1029439565f;   // A*0.044715
    float u = x * fmaf(B, x * x, A);
    float den = 1.0f + exp2f(-u);
#if __has_builtin(__builtin_amdgcn_rcpf)
    return x * __builtin_amdgcn_rcpf(den);
#else
    return x / den;
#endif
}

__device__ __forceinline__ unsigned short f2h(float x) {
    _Float16 h = (_Float16)x;
    return __builtin_bit_cast(unsigned short, h);
}

__device__ __forceinline__ float h2f_(unsigned short u) {
    return (float)__builtin_bit_cast(_Float16, u);
}

__device__ __forceinline__ h2 u2h2(unsigned int u) {
    return __builtin_bit_cast(h2, u);
}

__device__ __forceinline__ void gld_lds16(const void* g, void* l) {
    __builtin_amdgcn_global_load_lds(
        (const __attribute__((address_space(1))) unsigned int*)g,
        (__attribute__((address_space(3))) unsigned int*)l,
        16, 0, 0);
}

// ---------------------------------------------------------------------------
// Fused MLP: hpre = gelu(embA @ W1 + b1) @ W2 + b2, with per-row sum/sumsq
// atomics into st1/st2. One block = 64 rows. A staged in LDS once; W1T/W2T
// B-fragments read DIRECTLY from global (both L2-resident, 0.5 MB each);
// the 64x1024 gelu intermediate never touches HBM (lives in P_lds 128-col
// slices). 4 waves in a 2x2 grid: per wave 32 rows x {64 P cols | 128 h cols}.
// ---------------------------------------------------------------------------
__global__ __launch_bounds__(256) void fused_mlp(
    const unsigned short* __restrict__ embA,   // [NPAD][256] f16
    const unsigned short* __restrict__ W1T,    // [1024][256] f16
    const unsigned short* __restrict__ W2T,    // [256][1024] f16
    const float* __restrict__ b1, const float* __restrict__ b2,
    unsigned short* __restrict__ hpre,         // [NPAD][256] f16
    float* __restrict__ st1, float* __restrict__ st2)
{
    __shared__ __align__(16) unsigned char A_lds[32768];   // 4 subtiles [64r][64k] swz
    __shared__ __align__(16) unsigned char P_lds[16384];   // [64r][128k] swz
    const int t = threadIdx.x;
    const int lane = t & 63;
    const int wv = t >> 6;
    const int wr = wv >> 1, wc = wv & 1;
    const int l16 = lane & 15;
    const int l4  = lane >> 4;
    const int row0 = blockIdx.x * 64;

    // stage A: 4 k-subtiles of [64 rows][64 k], pre-swizzled source
    const int srow = t >> 3, sslot = t & 7;
    const int schunk = sslot ^ (srow & 7);
    #pragma unroll
    for (int kt = 0; kt < 4; ++kt)
        #pragma unroll
        for (int i = 0; i < 2; ++i)
            gld_lds16(embA + (size_t)(row0 + i * 32 + srow) * 256 + kt * 64 + schunk * 8,
                      &A_lds[kt * 8192 + i * 4096 + t * 16]);

    f32x4 hacc[2][8] = {};

    __syncthreads();   // A staged

    for (int j = 0; j < 8; ++j) {
        // ---- phase 1: pacc = A @ W1T[j*128 + wc*64 + n*16 ...] ----
        f32x4 pacc[2][4] = {};
        #pragma unroll
        for (int kk = 0; kk < 8; ++kk) {       // 32-k chunks over K=256
            int kt = kk >> 1, hh = kk & 1;
            f16x8 af[2];
            #pragma unroll
            for (int m = 0; m < 2; ++m) {
                int r = wr * 32 + m * 16 + l16;
                int c = (hh * 4 + l4) ^ (r & 7);
                af[m] = *reinterpret_cast<const f16x8*>(&A_lds[kt * 8192 + r * 128 + c * 16]);
            }
            #pragma unroll
            for (int n = 0; n < 4; ++n) {
                int col = j * 128 + wc * 64 + n * 16 + l16;
                f16x8 bf = *reinterpret_cast<const f16x8*>(&W1T[(size_t)col * 256 + kk * 32 + l4 * 8]);
                #pragma unroll
                for (int m = 0; m < 2; ++m)
                    pacc[m][n] = __builtin_amdgcn_mfma_f32_16x16x32_f16(
                        af[m], bf, pacc[m][n], 0, 0, 0);
            }
        }
        __syncthreads();   // P_lds free (previous phase-2 reads done)
        // bias + gelu -> P_lds (swizzled)
        #pragma unroll
        for (int n = 0; n < 4; ++n) {
            int colg = j * 128 + wc * 64 + n * 16 + l16;
            float bv = b1[colg];
            int colp = wc * 64 + n * 16 + l16;      // 0..127 within P
            #pragma unroll
            for (int m = 0; m < 2; ++m) {
                #pragma unroll
                for (int rg = 0; rg < 4; ++rg) {
                    int r = wr * 32 + m * 16 + l4 * 4 + rg;
                    float v = gelu_f(pacc[m][n][rg] + bv);
                    int cch = (colp >> 3) ^ (r & 7);
                    *reinterpret_cast<unsigned short*>(
                        &P_lds[r * 256 + cch * 16 + (colp & 7) * 2]) = f2h(v);
                }
            }
        }
        __syncthreads();   // P ready
        // ---- phase 2: hacc += P @ W2T[:, j*128 ...] ----
        #pragma unroll
        for (int kk = 0; kk < 4; ++kk) {       // 32-k chunks over 128
            f16x8 af[2];
            #pragma unroll
            for (int m = 0; m < 2; ++m) {
                int r = wr * 32 + m * 16 + l16;
                int c = (kk * 4 + l4) ^ (r & 7);
                af[m] = *reinterpret_cast<const f16x8*>(&P_lds[r * 256 + c * 16]);
            }
            #pragma unroll
            for (int n = 0; n < 8; ++n) {
                int col = wc * 128 + n * 16 + l16;
                f16x8 bf = *reinterpret_cast<const f16x8*>(
                    &W2T[(size_t)col * 1024 + j * 128 + kk * 32 + l4 * 8]);
                #pragma unroll
                for (int m = 0; m < 2; ++m)
                    hacc[m][n] = __builtin_amdgcn_mfma_f32_16x16x32_f16(
                        af[m], bf, hacc[m][n], 0, 0, 0);
            }
        }
        // next iteration's first barrier protects P_lds
    }

    // epilogue: + b2, row stats, write hpre
    float bv2[8];
    #pragma unroll
    for (int n = 0; n < 8; ++n) bv2[n] = b2[wc * 128 + n * 16 + l16];

    #pragma unroll
    for (int m = 0; m < 2; ++m) {
        #pragma unroll
        for (int rg = 0; rg < 4; ++rg) {
            int row = row0 + wr * 32 + m * 16 + l4 * 4 + rg;
            float s1l = 0.f, s2l = 0.f;
            #pragma unroll
            for (int n = 0; n < 8; ++n) {
                float v = hacc[m][n][rg] + bv2[n];
                s1l += v; s2l += v * v;
                if (row < NN)
                    hpre[(size_t)row * 256 + wc * 128 + n * 16 + l16] = f2h(v);
            }
            #pragma unroll
            for (int o = 1; o < 16; o <<= 1) {
                s1l += __shfl_xor(s1l, o);
                s2l += __shfl_xor(s2l, o);
            }
            if (l16 == 0 && row < NN) {
                atomicAdd(&st1[row], s1l);
                atomicAdd(&st2[row], s2l);
            }
        }
    }
}

// ---------------------------------------------------------------------------
// C[M,Nc] = A_f16[M,K] @ BT_f16[Nc,K]^T with LN fold (kept for the q|k1
// projection); 128x128 tile, BK=64, 4 waves, global_load_lds, XOR swizzle.
// ---------------------------------------------------------------------------
__global__ __launch_bounds__(256) void mfma_gemm_ln(
    const unsigned short* __restrict__ A,
    const unsigned short* __restrict__ BT,
    const float* __restrict__ bias,
    unsigned short* __restrict__ C,
    int M, int K, int Nc,
    const float* __restrict__ rs1, const float* __restrict__ rs2,
    const float* __restrict__ uvec)
{
    __shared__ __align__(16) unsigned char lds[32768];
    const int t    = threadIdx.x;
    const int lane = t & 63;
    const int wv   = t >> 6;
    const int wr   = wv >> 1, wc = wv & 1;
    const int row0 = blockIdx.y * 128;
    const int col0 = blockIdx.x * 128;

    f32x4 acc[4][4] = {};

    const int srow  = t >> 3;
    const int sslot = t & 7;
    const int schunk = sslot ^ (srow & 7);

    const unsigned short* Ab = A  + (size_t)row0 * K;
    const unsigned short* Bb = BT + (size_t)col0 * K;

    for (int k0 = 0; k0 < K; k0 += 64) {
        #pragma unroll
        for (int i = 0; i < 4; ++i)
            gld_lds16(Ab + (size_t)(i * 32 + srow) * K + k0 + schunk * 8,
                      &lds[i * 4096 + t * 16]);
        #pragma unroll
        for (int i = 0; i < 4; ++i)
            gld_lds16(Bb + (size_t)(i * 32 + srow) * K + k0 + schunk * 8,
                      &lds[16384 + i * 4096 + t * 16]);
        __syncthreads();

        #pragma unroll
        for (int kk = 0; kk < 2; ++kk) {
            f16x8 af[4], bf[4];
            #pragma unroll
            for (int m = 0; m < 4; ++m) {
                int r  = wr * 64 + m * 16 + (lane & 15);
                int ch = (kk * 4 + (lane >> 4)) ^ (r & 7);
                af[m] = *reinterpret_cast<const f16x8*>(&lds[r * 128 + ch * 16]);
            }
            #pragma unroll
            for (int n = 0; n < 4; ++n) {
                int r  = wc * 64 + n * 16 + (lane & 15);
                int ch = (kk * 4 + (lane >> 4)) ^ (r & 7);
                bf[n] = *reinterpret_cast<const f16x8*>(&lds[16384 + r * 128 + ch * 16]);
            }
            #pragma unroll
            for (int m = 0; m < 4; ++m)
                #pragma unroll
                for (int n = 0; n < 4; ++n)
                    acc[m][n] = __builtin_amdgcn_mfma_f32_16x16x32_f16(
                        af[m], bf[n], acc[m][n], 0, 0, 0);
        }
        __syncthreads();
    }

    float bv[4], uv_[4];
    #pragma unroll
    for (int n = 0; n < 4; ++n) {
        int col = col0 + wc * 64 + n * 16 + (lane & 15);
        bv[n] = bias[col];
        uv_[n] = uvec[col];
    }

    #pragma unroll
    for (int m = 0; m < 4; ++m) {
        #pragma unroll
        for (int rg = 0; rg < 4; ++rg) {
            int row = row0 + wr * 64 + m * 16 + (lane >> 4) * 4 + rg;
            float S1 = rs1[row], S2 = rs2[row];
            float mu = S1 * (1.0f / HH);
            float var = S2 * (1.0f / HH) - mu * mu;
            float inv = rsqrtf(var + 1e-5f);
            float nmu = inv * mu;
            #pragma unroll
            for (int n = 0; n < 4; ++n) {
                float v = fmaf(inv, acc[m][n][rg], fmaf(-nmu, uv_[n], bv[n]));
                if (row < M) {
                    int col = col0 + wc * 64 + n * 16 + (lane & 15);
                    C[(size_t)row * Nc + col] = f2h(v);
                }
            }
        }
    }
}

// ---------------------------------------------------------------------------
// prep mega-kernel (unchanged from R9)
// ---------------------------------------------------------------------------
#define PB0 12500
#define PB1 (PB0 + 3125)
#define PB2 (PB1 + 1024)
#define PB3 (PB2 + 1024)
#define PB4 (PB3 + 256)
#define PB5 (PB4 + 256)
#define PB6 (PB5 + 3)
#define PB7 (PB6 + 2)
__global__ __launch_bounds__(256) void prep_kernel(
    const float* __restrict__ embedding, const float* __restrict__ scores,
    const float* __restrict__ W1, const float* __restrict__ W2,
    const float* __restrict__ Wl, const float* __restrict__ Wr,
    const float* __restrict__ ln_g, const float* __restrict__ ln_b,
    const float* __restrict__ bl, const float* __restrict__ br,
    const float* __restrict__ We, const float* __restrict__ be,
    const float* __restrict__ emb_table,
    unsigned short* __restrict__ embA, unsigned short* __restrict__ scoresb,
    unsigned short* __restrict__ W1T, unsigned short* __restrict__ W2T,
    unsigned short* __restrict__ WlrT, unsigned short* __restrict__ k2t,
    float* __restrict__ uvec, float* __restrict__ vvec)
{
    const int gb = blockIdx.x, t = threadIdx.x;
    if (gb < PB0) {
        int i = gb * 256 + t;
        float4 v = reinterpret_cast<const float4*>(embedding)[i];
        ushort4 o; o.x = f2h(v.x); o.y = f2h(v.y); o.z = f2h(v.z); o.w = f2h(v.w);
        reinterpret_cast<ushort4*>(embA)[i] = o;
    } else if (gb < PB1) {
        int i = (gb - PB0) * 256 + t;
        float4 v = reinterpret_cast<const float4*>(scores)[i];
        ushort4 o; o.x = f2h(v.x); o.y = f2h(v.y); o.z = f2h(v.z); o.w = f2h(v.w);
        reinterpret_cast<ushort4*>(scoresb)[i] = o;
    } else if (gb < PB2) {
        int o = (gb - PB1) * 256 + t;
        int c = o >> 8, r = o & 255;
        W1T[o] = f2h(W1[r * 1024 + c]);
    } else if (gb < PB3) {
        int o = (gb - PB2) * 256 + t;
        int c = o >> 10, r = o & 1023;
        W2T[o] = f2h(W2[r * 256 + c]);
    } else if (gb < PB4) {
        int o = (gb - PB3) * 256 + t;
        int c = o >> 8, r = o & 255;
        WlrT[o] = f2h(Wl[r * 256 + c] * ln_g[r] * QSCALE);
    } else if (gb < PB5) {
        int o = (gb - PB4) * 256 + t;
        int c = o >> 8, r = o & 255;
        WlrT[65536 + o] = f2h(Wr[r * 256 + c] * ln_g[r]);
    } else if (gb < PB6) {
        int ty = gb - PB5;
        float a = be[t];
        #pragma unroll
        for (int f = 0; f < 20; ++f)
            a += gelu_f(emb_table[ty * 20 + f]) * We[f * 256 + t];
        k2t[ty * 256 + t] = f2h(a);
    } else {
        int c = (gb - PB6) * 256 + t;
        int cc = c & 255;
        const float* W = (c < 256) ? Wl : Wr;
        float u = 0.f, v = 0.f;
        for (int j = 0; j < 256; ++j) {
            float w = W[j * 256 + cc];
            u += ln_g[j] * w;
            v += ln_b[j] * w;
        }
        float sc = (c < 256) ? QSCALE : 1.0f;
        uvec[c] = u * sc;
        vvec[c] = (v + ((c < 256) ? bl[cc] : br[cc])) * sc;
    }
}

// ---- CSR build ----
__global__ void hist_kernel(const int* __restrict__ dst, int* __restrict__ cnt)
{
    int e = blockIdx.x * 256 + threadIdx.x;
    if (e < EE) atomicAdd(&cnt[dst[e]], 1);
}

__global__ __launch_bounds__(256) void scan_part(
    const int* __restrict__ cnt, int* __restrict__ off, int* __restrict__ bsum)
{
    int b = blockIdx.x, t = threadIdx.x;
    int idx = b * 256 + t;
    int v = (idx < NN) ? cnt[idx] : 0;
    int inc = v;
    #pragma unroll
    for (int o = 1; o < 64; o <<= 1) {
        int u = __shfl_up(inc, o);
        if ((t & 63) >= o) inc += u;
    }
    __shared__ int wt[4];
    if ((t & 63) == 63) wt[t >> 6] = inc;
    __syncthreads();
    int wo = 0;
    #pragma unroll
    for (int w = 0; w < 4; ++w) if (w < (t >> 6)) wo += wt[w];
    if (idx < NN) off[idx] = wo + inc - v;
    if (t == 255) bsum[b] = wo + inc;
}

__global__ __launch_bounds__(256) void scan_sums(int* __restrict__ bsum)
{
    int t = threadIdx.x;
    int v = (t < NB) ? bsum[t] : 0;
    int inc = v;
    #pragma unroll
    for (int o = 1; o < 64; o <<= 1) {
        int u = __shfl_up(inc, o);
        if ((t & 63) >= o) inc += u;
    }
    __shared__ int wt[4];
    if ((t & 63) == 63) wt[t >> 6] = inc;
    __syncthreads();
    int wo = 0;
    #pragma unroll
    for (int w = 0; w < 4; ++w) if (w < (t >> 6)) wo += wt[w];
    if (t < NB) bsum[t] = wo + inc - v;
}

__global__ void scan_add(int* __restrict__ off, const int* __restrict__ bsum,
                         int* __restrict__ cur)
{
    int b = blockIdx.x, t = threadIdx.x;
    int idx = b * 256 + t;
    if (idx < NN) {
        int o = off[idx] + bsum[b];
        off[idx] = o;
        cur[idx] = o;
    }
    if (idx == 0) off[NN] = EE;
}

__global__ void fill_kernel(const int* __restrict__ src, const int* __restrict__ dst,
                            const int* __restrict__ typ, int* __restrict__ cur,
                            unsigned int* __restrict__ pack)
{
    int e = blockIdx.x * 256 + threadIdx.x;
    if (e < 8) pack[EE + e] = 0;
    if (e >= EE) return;
    int pos = atomicAdd(&cur[dst[e]], 1);
    pack[pos] = ((unsigned int)src[e] << 10) | (unsigned int)typ[e];
}

// ---------------------------------------------------------------------------
// fused per-dst attention (R6-proven structure: packed-h2 dot, NOT fdot2)
// ---------------------------------------------------------------------------
__global__ __launch_bounds__(256) void fused_edge_kernel(
    const unsigned short* __restrict__ qk,      // f16 [NPAD][512]: [q*QSCALE | k1]
    const unsigned short* __restrict__ k2t,     // f16 [3][256]
    const int* __restrict__ off, const unsigned int* __restrict__ pack,
    const unsigned short* __restrict__ scoresb, // f16 [NN][64]
    float* __restrict__ out)
{
    const int t = threadIdx.x, lane = t & 63;
    const int sub = lane & 31;
    const int g = lane >> 5;
    const int d = blockIdx.x * 4 + (t >> 6);
    if (d >= NN) return;
    const int beg = off[d], end = off[d + 1];
    if (beg == end) { out[(size_t)d * CC + lane] = 0.f; return; }

    const char* qkb = (const char*)qk;

    uint4 qv = *reinterpret_cast<const uint4*>(qkb + (size_t)d * 1024 + sub * 16);
    h2 q0 = u2h2(qv.x), q1 = u2h2(qv.y), q2 = u2h2(qv.z), q3 = u2h2(qv.w);

    auto dot = [&](uint4 kv) {
        h2 p = q0 * u2h2(kv.x) + q1 * u2h2(kv.y) + q2 * u2h2(kv.z) + q3 * u2h2(kv.w);
        return (float)p[0] + (float)p[1];
    };

    float qe0, qe1, qe2;
    {
        uint4 k0v = *reinterpret_cast<const uint4*>((const char*)k2t + 0 * 512 + sub * 16);
        uint4 k1v = *reinterpret_cast<const uint4*>((const char*)k2t + 1 * 512 + sub * 16);
        uint4 k2v = *reinterpret_cast<const uint4*>((const char*)k2t + 2 * 512 + sub * 16);
        qe0 = dot(k0v); qe1 = dot(k1v); qe2 = dot(k2v);
        #pragma unroll
        for (int o = 1; o < 32; o <<= 1) {
            qe0 += __shfl_xor(qe0, o);
            qe1 += __shfl_xor(qe1, o);
            qe2 += __shfl_xor(qe2, o);
        }
    }
    auto qsel = [&](unsigned pk) {
        int ty = pk & 3;
        return (ty == 0) ? qe0 : (ty == 1) ? qe1 : qe2;
    };

    unsigned pkA = pack[beg], pkB = pack[beg + 1];
    uint4 kv = *reinterpret_cast<const uint4*>(qkb + ((g ? pkB : pkA) & ~3u) + 512 + sub * 16);
    float scA = h2f_(scoresb[((pkA & ~3u) >> 4) + lane]);
    float scB = h2f_(scoresb[((pkB & ~3u) >> 4) + lane]);

    float m = -INFINITY, s = 0.f, acc = 0.f;

    for (int i = beg; i < end; i += 2) {
        int inext = (i + 2 < end) ? i + 2 : i;
        unsigned npA = pack[inext], npB = pack[inext + 1];
        uint4 nkv = *reinterpret_cast<const uint4*>(qkb + ((g ? npB : npA) & ~3u) + 512 + sub * 16);
        float nsA = h2f_(scoresb[((npA & ~3u) >> 4) + lane]);
        float nsB = h2f_(scoresb[((npB & ~3u) >> 4) + lane]);

        float a = dot(kv);
        #pragma unroll
        for (int o = 1; o < 32; o <<= 1) a += __shfl_xor(a, o);
        float other = __shfl_xor(a, 32);
        float aA = (g ? other : a) + qsel(pkA);
        float aB = (g ? a : other) + qsel(pkB);
        if (i + 1 >= end) aB = -INFINITY;

        float nm = fmaxf(m, fmaxf(aA, aB));
        float c_ = exp2f(m - nm);
        float w0 = exp2f(aA - nm);
        float w1 = exp2f(aB - nm);
        s = s * c_ + w0 + w1;
        acc = fmaf(acc, c_, fmaf(w0, scA, w1 * scB));
        m = nm;

        pkA = npA; pkB = npB; kv = nkv; scA = nsA; scB = nsB;
    }
    out[(size_t)d * CC + lane] = acc / s;
}

extern "C" void kernel_launch(void* const* d_in, const int* in_sizes, int n_in,
                              void* d_out, int out_size, void* d_ws, size_t ws_size,
                              hipStream_t stream) {
    const float* embedding = (const float*)d_in[0];
    const float* scores    = (const float*)d_in[1];
    const int*   src       = (const int*)d_in[2];
    const int*   dst       = (const int*)d_in[3];
    const int*   typ       = (const int*)d_in[4];
    const float* W1  = (const float*)d_in[5];
    const float* b1  = (const float*)d_in[6];
    const float* W2  = (const float*)d_in[7];
    const float* b2  = (const float*)d_in[8];
    const float* ln_g = (const float*)d_in[9];
    const float* ln_b = (const float*)d_in[10];
    const float* Wl  = (const float*)d_in[11];
    const float* bl  = (const float*)d_in[12];
    const float* Wr  = (const float*)d_in[13];
    const float* br  = (const float*)d_in[14];
    const float* We  = (const float*)d_in[15];
    const float* be  = (const float*)d_in[16];
    const float* emb_table = (const float*)d_in[17];
    float* out = (float*)d_out;
    (void)in_sizes; (void)n_in; (void)out_size; (void)ws_size;

    // ---- workspace carve-up (256-aligned chunks) ----
    char* w = (char*)d_ws;
    auto take = [&](size_t bytes) {
        char* p = w;
        w += (bytes + 255) & ~(size_t)255;
        return p;
    };
    unsigned short* embA = (unsigned short*)take((size_t)NPAD * HH * 2);
    unsigned short* hpre = (unsigned short*)take((size_t)NPAD * HH * 2);
    unsigned short* qk   = (unsigned short*)take((size_t)NPAD * 512 * 2);
    unsigned short* W1T  = (unsigned short*)take((size_t)4 * HH * HH * 2);
    unsigned short* W2T  = (unsigned short*)take((size_t)HH * 4 * HH * 2);
    unsigned short* WlrT = (unsigned short*)take((size_t)512 * HH * 2);
    unsigned short* k2t  = (unsigned short*)take(2048);
    unsigned short* scoresb = (unsigned short*)take((size_t)NN * CC * 2);
    float*          uvec = (float*)take(512 * 4);
    float*          vvec = (float*)take(512 * 4);
    int*            cnt  = (int*)take((size_t)NPAD * 4);
    float*          st1  = (float*)take((size_t)NPAD * 4);
    float*          st2  = (float*)take((size_t)NPAD * 4);
    int*            offb = (int*)take((size_t)(NN + 1) * 4);
    int*            cur  = (int*)take((size_t)NN * 4);
    int*            bsum = (int*)take(256 * 4);
    unsigned int*   pack = (unsigned int*)take((size_t)EE * 4 + 64);

    hipMemsetAsync(cnt, 0, (size_t)3 * NPAD * 4, stream);

    // ---- one prep launch ----
    prep_kernel<<<PB7, 256, 0, stream>>>(
        embedding, scores, W1, W2, Wl, Wr, ln_g, ln_b, bl, br, We, be, emb_table,
        embA, scoresb, W1T, W2T, WlrT, k2t, uvec, vvec);

    // ---- CSR build ----
    hist_kernel<<<(EE + 255) / 256, 256, 0, stream>>>(dst, cnt);
    scan_part<<<NB, 256, 0, stream>>>(cnt, offb, bsum);
    scan_sums<<<1, 256, 0, stream>>>(bsum);
    scan_add<<<NB, 256, 0, stream>>>(offb, bsum, cur);
    fill_kernel<<<(EE + 255) / 256, 256, 0, stream>>>(src, dst, typ, cur, pack);

    // ---- fused MLP: hpre = gelu(embA@W1+b1)@W2+b2, stats in one pass ----
    fused_mlp<<<NPAD / 64, 256, 0, stream>>>(
        embA, W1T, W2T, b1, b2, hpre, st1, st2);

    // ---- q|k1 projection with fused LayerNorm ----
    dim3 gq(512 / 128, NPAD / 128);
    mfma_gemm_ln<<<gq, 256, 0, stream>>>(
        hpre, WlrT, vvec, qk, NN, HH, 512, st1, st2, uvec);

    // ---- fused edge phase ----
    fused_edge_kernel<<<(NN + 3) / 4, 256, 0, stream>>>(qk, k2t, offb, pack, scoresb, out);
}

// Round 11
// 377.752 us; speedup vs baseline: 1.5597x; 1.5597x over previous
//
#include <hip/hip_runtime.h>
#include <math.h>

#define NN 50000
#define EE 800000
#define HH 256
#define CC 64
#define NPAD 50048          // NN rounded to 128
#define NB 196              // scan blocks = ceil(NN/256)
#define QSCALE 0.09016843798f   // (1/16) * log2(e): folds 1/sqrt(H) and exp->exp2

typedef _Float16 f16x8 __attribute__((ext_vector_type(8)));
typedef _Float16 h2 __attribute__((ext_vector_type(2)));
typedef float f32x4 __attribute__((ext_vector_type(4)));

// exact tanh-gelu via sigmoid identity: 0.5x(1+tanh(z)) = x / (1 + exp(-2z))
__device__ __forceinline__ float gelu_f(float x) {
    const float A = 2.302118074f;    // 2*log2(e)*sqrt(2/pi)
    const float B = 0.1029439565f;   // A*0.044715
    float u = x * fmaf(B, x * x, A);
    float den = 1.0f + exp2f(-u);
#if __has_builtin(__builtin_amdgcn_rcpf)
    return x * __builtin_amdgcn_rcpf(den);
#else
    return x / den;
#endif
}

__device__ __forceinline__ unsigned short f2h(float x) {
    _Float16 h = (_Float16)x;
    return __builtin_bit_cast(unsigned short, h);
}

__device__ __forceinline__ float h2f_(unsigned short u) {
    return (float)__builtin_bit_cast(_Float16, u);
}

__device__ __forceinline__ h2 u2h2(unsigned int u) {
    return __builtin_bit_cast(h2, u);
}

__device__ __forceinline__ void gld_lds16(const void* g, void* l) {
    __builtin_amdgcn_global_load_lds(
        (const __attribute__((address_space(1))) unsigned int*)g,
        (__attribute__((address_space(3))) unsigned int*)l,
        16, 0, 0);
}

// ---------------------------------------------------------------------------
// C[M,Nc] = act(A_f16[M,K] @ BT_f16[Nc,K]^T + bias); 128x128 tile, BK=64,
// 4 waves, 16x16x32 f16 MFMA, global_load_lds, XOR-swizzled LDS.
// (R6/R9-proven structure: 32KB LDS single-buffer.)
// STATS:  atomically accumulate per-row sum/sumsq of the output into st1/st2.
// LNFOLD: out = inv*raw - inv*mu*u[col] + bias[col], mu/inv from rs1/rs2.
// ---------------------------------------------------------------------------
template<int ACT, bool OUT_F16, bool STATS, bool LNFOLD>
__global__ __launch_bounds__(256) void mfma_gemm(
    const unsigned short* __restrict__ A,
    const unsigned short* __restrict__ BT,
    const float* __restrict__ bias,
    void* __restrict__ C,
    int M, int K, int Nc,
    float* __restrict__ st1, float* __restrict__ st2,
    const float* __restrict__ rs1, const float* __restrict__ rs2,
    const float* __restrict__ uvec)
{
    __shared__ __align__(16) unsigned char lds[32768]; // A: [0,16K), B: [16K,32K)
    const int t    = threadIdx.x;
    const int lane = t & 63;
    const int wv   = t >> 6;
    const int wr   = wv >> 1, wc = wv & 1;
    const int row0 = blockIdx.y * 128;
    const int col0 = blockIdx.x * 128;

    f32x4 acc[4][4] = {};

    const int srow  = t >> 3;               // 0..31
    const int sslot = t & 7;
    const int schunk = sslot ^ (srow & 7);  // XOR-swizzled k-chunk slot

    const unsigned short* Ab = A  + (size_t)row0 * K;
    const unsigned short* Bb = BT + (size_t)col0 * K;

    for (int k0 = 0; k0 < K; k0 += 64) {
        #pragma unroll
        for (int i = 0; i < 4; ++i)
            gld_lds16(Ab + (size_t)(i * 32 + srow) * K + k0 + schunk * 8,
                      &lds[i * 4096 + t * 16]);
        #pragma unroll
        for (int i = 0; i < 4; ++i)
            gld_lds16(Bb + (size_t)(i * 32 + srow) * K + k0 + schunk * 8,
                      &lds[16384 + i * 4096 + t * 16]);
        __syncthreads();

        #pragma unroll
        for (int kk = 0; kk < 2; ++kk) {
            f16x8 af[4], bf[4];
            #pragma unroll
            for (int m = 0; m < 4; ++m) {
                int r  = wr * 64 + m * 16 + (lane & 15);
                int ch = (kk * 4 + (lane >> 4)) ^ (r & 7);
                af[m] = *reinterpret_cast<const f16x8*>(&lds[r * 128 + ch * 16]);
            }
            #pragma unroll
            for (int n = 0; n < 4; ++n) {
                int r  = wc * 64 + n * 16 + (lane & 15);
                int ch = (kk * 4 + (lane >> 4)) ^ (r & 7);
                bf[n] = *reinterpret_cast<const f16x8*>(&lds[16384 + r * 128 + ch * 16]);
            }
            #pragma unroll
            for (int m = 0; m < 4; ++m)
                #pragma unroll
                for (int n = 0; n < 4; ++n)
                    acc[m][n] = __builtin_amdgcn_mfma_f32_16x16x32_f16(
                        af[m], bf[n], acc[m][n], 0, 0, 0);
        }
        __syncthreads();
    }

    float bv[4], uv_[4];
    #pragma unroll
    for (int n = 0; n < 4; ++n) {
        int col = col0 + wc * 64 + n * 16 + (lane & 15);
        bv[n] = bias[col];
        if (LNFOLD) uv_[n] = uvec[col];
    }

    #pragma unroll
    for (int m = 0; m < 4; ++m) {
        #pragma unroll
        for (int rg = 0; rg < 4; ++rg) {
            int row = row0 + wr * 64 + m * 16 + (lane >> 4) * 4 + rg;
            float inv = 0.f, nmu = 0.f;
            if (LNFOLD) {
                float S1 = rs1[row], S2 = rs2[row];
                float mu = S1 * (1.0f / HH);
                float var = S2 * (1.0f / HH) - mu * mu;
                inv = rsqrtf(var + 1e-5f);
                nmu = inv * mu;
            }
            float s1l = 0.f, s2l = 0.f;
            #pragma unroll
            for (int n = 0; n < 4; ++n) {
                float v;
                if (LNFOLD) v = fmaf(inv, acc[m][n][rg], fmaf(-nmu, uv_[n], bv[n]));
                else        v = acc[m][n][rg] + bv[n];
                if (ACT) v = gelu_f(v);
                if (STATS) { s1l += v; s2l += v * v; }
                if (row < M) {
                    int col = col0 + wc * 64 + n * 16 + (lane & 15);
                    if (OUT_F16) ((unsigned short*)C)[(size_t)row * Nc + col] = f2h(v);
                    else         ((float*)C)[(size_t)row * Nc + col] = v;
                }
            }
            if (STATS) {
                #pragma unroll
                for (int o = 1; o < 16; o <<= 1) {
                    s1l += __shfl_xor(s1l, o);
                    s2l += __shfl_xor(s2l, o);
                }
                if ((lane & 15) == 0 && row < M) {
                    atomicAdd(&st1[row], s1l);
                    atomicAdd(&st2[row], s2l);
                }
            }
        }
    }
}

// ---------------------------------------------------------------------------
// prep mega-kernel: f2h(embedding), f2h(scores), W1T, W2T, WlrT (g-folded,
// q-half scaled by QSCALE), k2 table, u/v fold vectors — one launch.
// ---------------------------------------------------------------------------
#define PB0 12500
#define PB1 (PB0 + 3125)
#define PB2 (PB1 + 1024)
#define PB3 (PB2 + 1024)
#define PB4 (PB3 + 256)
#define PB5 (PB4 + 256)
#define PB6 (PB5 + 3)
#define PB7 (PB6 + 2)
__global__ __launch_bounds__(256) void prep_kernel(
    const float* __restrict__ embedding, const float* __restrict__ scores,
    const float* __restrict__ W1, const float* __restrict__ W2,
    const float* __restrict__ Wl, const float* __restrict__ Wr,
    const float* __restrict__ ln_g, const float* __restrict__ ln_b,
    const float* __restrict__ bl, const float* __restrict__ br,
    const float* __restrict__ We, const float* __restrict__ be,
    const float* __restrict__ emb_table,
    unsigned short* __restrict__ embA, unsigned short* __restrict__ scoresb,
    unsigned short* __restrict__ W1T, unsigned short* __restrict__ W2T,
    unsigned short* __restrict__ WlrT, unsigned short* __restrict__ k2t,
    float* __restrict__ uvec, float* __restrict__ vvec)
{
    const int gb = blockIdx.x, t = threadIdx.x;
    if (gb < PB0) {
        int i = gb * 256 + t;
        float4 v = reinterpret_cast<const float4*>(embedding)[i];
        ushort4 o; o.x = f2h(v.x); o.y = f2h(v.y); o.z = f2h(v.z); o.w = f2h(v.w);
        reinterpret_cast<ushort4*>(embA)[i] = o;
    } else if (gb < PB1) {
        int i = (gb - PB0) * 256 + t;
        float4 v = reinterpret_cast<const float4*>(scores)[i];
        ushort4 o; o.x = f2h(v.x); o.y = f2h(v.y); o.z = f2h(v.z); o.w = f2h(v.w);
        reinterpret_cast<ushort4*>(scoresb)[i] = o;
    } else if (gb < PB2) {
        int o = (gb - PB1) * 256 + t;
        int c = o >> 8, r = o & 255;
        W1T[o] = f2h(W1[r * 1024 + c]);
    } else if (gb < PB3) {
        int o = (gb - PB2) * 256 + t;
        int c = o >> 10, r = o & 1023;
        W2T[o] = f2h(W2[r * 256 + c]);
    } else if (gb < PB4) {
        int o = (gb - PB3) * 256 + t;
        int c = o >> 8, r = o & 255;
        WlrT[o] = f2h(Wl[r * 256 + c] * ln_g[r] * QSCALE);
    } else if (gb < PB5) {
        int o = (gb - PB4) * 256 + t;
        int c = o >> 8, r = o & 255;
        WlrT[65536 + o] = f2h(Wr[r * 256 + c] * ln_g[r]);
    } else if (gb < PB6) {
        int ty = gb - PB5;
        float a = be[t];
        #pragma unroll
        for (int f = 0; f < 20; ++f)
            a += gelu_f(emb_table[ty * 20 + f]) * We[f * 256 + t];
        k2t[ty * 256 + t] = f2h(a);
    } else {
        int c = (gb - PB6) * 256 + t;
        int cc = c & 255;
        const float* W = (c < 256) ? Wl : Wr;
        float u = 0.f, v = 0.f;
        for (int j = 0; j < 256; ++j) {
            float w = W[j * 256 + cc];
            u += ln_g[j] * w;
            v += ln_b[j] * w;
        }
        float sc = (c < 256) ? QSCALE : 1.0f;
        uvec[c] = u * sc;
        vvec[c] = (v + ((c < 256) ? bl[cc] : br[cc])) * sc;
    }
}

// ---- CSR build ----
__global__ void hist_kernel(const int* __restrict__ dst, int* __restrict__ cnt)
{
    int e = blockIdx.x * 256 + threadIdx.x;
    if (e < EE) atomicAdd(&cnt[dst[e]], 1);
}

__global__ __launch_bounds__(256) void scan_part(
    const int* __restrict__ cnt, int* __restrict__ off, int* __restrict__ bsum)
{
    int b = blockIdx.x, t = threadIdx.x;
    int idx = b * 256 + t;
    int v = (idx < NN) ? cnt[idx] : 0;
    int inc = v;
    #pragma unroll
    for (int o = 1; o < 64; o <<= 1) {
        int u = __shfl_up(inc, o);
        if ((t & 63) >= o) inc += u;
    }
    __shared__ int wt[4];
    if ((t & 63) == 63) wt[t >> 6] = inc;
    __syncthreads();
    int wo = 0;
    #pragma unroll
    for (int w = 0; w < 4; ++w) if (w < (t >> 6)) wo += wt[w];
    if (idx < NN) off[idx] = wo + inc - v;
    if (t == 255) bsum[b] = wo + inc;
}

__global__ __launch_bounds__(256) void scan_sums(int* __restrict__ bsum)
{
    int t = threadIdx.x;
    int v = (t < NB) ? bsum[t] : 0;
    int inc = v;
    #pragma unroll
    for (int o = 1; o < 64; o <<= 1) {
        int u = __shfl_up(inc, o);
        if ((t & 63) >= o) inc += u;
    }
    __shared__ int wt[4];
    if ((t & 63) == 63) wt[t >> 6] = inc;
    __syncthreads();
    int wo = 0;
    #pragma unroll
    for (int w = 0; w < 4; ++w) if (w < (t >> 6)) wo += wt[w];
    if (t < NB) bsum[t] = wo + inc - v;
}

__global__ void scan_add(int* __restrict__ off, const int* __restrict__ bsum,
                         int* __restrict__ cur)
{
    int b = blockIdx.x, t = threadIdx.x;
    int idx = b * 256 + t;
    if (idx < NN) {
        int o = off[idx] + bsum[b];
        off[idx] = o;
        cur[idx] = o;
    }
    if (idx == 0) off[NN] = EE;
}

// pack entry = (src << 10) | ty  -> byte offset of the qk row, type in low bits
__global__ void fill_kernel(const int* __restrict__ src, const int* __restrict__ dst,
                            const int* __restrict__ typ, int* __restrict__ cur,
                            unsigned int* __restrict__ pack)
{
    int e = blockIdx.x * 256 + threadIdx.x;
    if (e < 8) pack[EE + e] = 0;
    if (e >= EE) return;
    int pos = atomicAdd(&cur[dst[e]], 1);
    pack[pos] = ((unsigned int)src[e] << 10) | (unsigned int)typ[e];
}

// ---------------------------------------------------------------------------
// fused per-dst attention (R6-proven structure: packed-h2 dot)
// ---------------------------------------------------------------------------
__global__ __launch_bounds__(256) void fused_edge_kernel(
    const unsigned short* __restrict__ qk,      // f16 [NPAD][512]: [q*QSCALE | k1]
    const unsigned short* __restrict__ k2t,     // f16 [3][256]
    const int* __restrict__ off, const unsigned int* __restrict__ pack,
    const unsigned short* __restrict__ scoresb, // f16 [NN][64]
    float* __restrict__ out)
{
    const int t = threadIdx.x, lane = t & 63;
    const int sub = lane & 31;
    const int g = lane >> 5;
    const int d = blockIdx.x * 4 + (t >> 6);
    if (d >= NN) return;
    const int beg = off[d], end = off[d + 1];
    if (beg == end) { out[(size_t)d * CC + lane] = 0.f; return; }

    const char* qkb = (const char*)qk;

    uint4 qv = *reinterpret_cast<const uint4*>(qkb + (size_t)d * 1024 + sub * 16);
    h2 q0 = u2h2(qv.x), q1 = u2h2(qv.y), q2 = u2h2(qv.z), q3 = u2h2(qv.w);

    auto dot = [&](uint4 kv) {
        h2 p = q0 * u2h2(kv.x) + q1 * u2h2(kv.y) + q2 * u2h2(kv.z) + q3 * u2h2(kv.w);
        return (float)p[0] + (float)p[1];
    };

    float qe0, qe1, qe2;
    {
        uint4 k0v = *reinterpret_cast<const uint4*>((const char*)k2t + 0 * 512 + sub * 16);
        uint4 k1v = *reinterpret_cast<const uint4*>((const char*)k2t + 1 * 512 + sub * 16);
        uint4 k2v = *reinterpret_cast<const uint4*>((const char*)k2t + 2 * 512 + sub * 16);
        qe0 = dot(k0v); qe1 = dot(k1v); qe2 = dot(k2v);
        #pragma unroll
        for (int o = 1; o < 32; o <<= 1) {
            qe0 += __shfl_xor(qe0, o);
            qe1 += __shfl_xor(qe1, o);
            qe2 += __shfl_xor(qe2, o);
        }
    }
    auto qsel = [&](unsigned pk) {
        int ty = pk & 3;
        return (ty == 0) ? qe0 : (ty == 1) ? qe1 : qe2;
    };

    unsigned pkA = pack[beg], pkB = pack[beg + 1];
    uint4 kv = *reinterpret_cast<const uint4*>(qkb + ((g ? pkB : pkA) & ~3u) + 512 + sub * 16);
    float scA = h2f_(scoresb[((pkA & ~3u) >> 4) + lane]);
    float scB = h2f_(scoresb[((pkB & ~3u) >> 4) + lane]);

    float m = -INFINITY, s = 0.f, acc = 0.f;

    for (int i = beg; i < end; i += 2) {
        int inext = (i + 2 < end) ? i + 2 : i;
        unsigned npA = pack[inext], npB = pack[inext + 1];
        uint4 nkv = *reinterpret_cast<const uint4*>(qkb + ((g ? npB : npA) & ~3u) + 512 + sub * 16);
        float nsA = h2f_(scoresb[((npA & ~3u) >> 4) + lane]);
        float nsB = h2f_(scoresb[((npB & ~3u) >> 4) + lane]);

        float a = dot(kv);
        #pragma unroll
        for (int o = 1; o < 32; o <<= 1) a += __shfl_xor(a, o);
        float other = __shfl_xor(a, 32);
        float aA = (g ? other : a) + qsel(pkA);
        float aB = (g ? a : other) + qsel(pkB);
        if (i + 1 >= end) aB = -INFINITY;

        float nm = fmaxf(m, fmaxf(aA, aB));
        float c_ = exp2f(m - nm);
        float w0 = exp2f(aA - nm);
        float w1 = exp2f(aB - nm);
        s = s * c_ + w0 + w1;
        acc = fmaf(acc, c_, fmaf(w0, scA, w1 * scB));
        m = nm;

        pkA = npA; pkB = npB; kv = nkv; scA = nsA; scB = nsB;
    }
    out[(size_t)d * CC + lane] = acc / s;
}

extern "C" void kernel_launch(void* const* d_in, const int* in_sizes, int n_in,
                              void* d_out, int out_size, void* d_ws, size_t ws_size,
                              hipStream_t stream) {
    const float* embedding = (const float*)d_in[0];
    const float* scores    = (const float*)d_in[1];
    const int*   src       = (const int*)d_in[2];
    const int*   dst       = (const int*)d_in[3];
    const int*   typ       = (const int*)d_in[4];
    const float* W1  = (const float*)d_in[5];
    const float* b1  = (const float*)d_in[6];
    const float* W2  = (const float*)d_in[7];
    const float* b2  = (const float*)d_in[8];
    const float* ln_g = (const float*)d_in[9];
    const float* ln_b = (const float*)d_in[10];
    const float* Wl  = (const float*)d_in[11];
    const float* bl  = (const float*)d_in[12];
    const float* Wr  = (const float*)d_in[13];
    const float* br  = (const float*)d_in[14];
    const float* We  = (const float*)d_in[15];
    const float* be  = (const float*)d_in[16];
    const float* emb_table = (const float*)d_in[17];
    float* out = (float*)d_out;
    (void)in_sizes; (void)n_in; (void)out_size; (void)ws_size;

    // ---- workspace carve-up (256-aligned chunks) ----
    char* w = (char*)d_ws;
    auto take = [&](size_t bytes) {
        char* p = w;
        w += (bytes + 255) & ~(size_t)255;
        return p;
    };
    unsigned short* embA = (unsigned short*)take((size_t)NPAD * HH * 2);
    unsigned short* hpre = (unsigned short*)take((size_t)NPAD * HH * 2);
    // BIG buffer: Gch [NPAD][1024] f16 during the MLP; first half reused as
    // qk [NPAD][512] f16 (Gch dead once GEMM2 reads it).
    unsigned short* Gch  = (unsigned short*)take((size_t)NPAD * 1024 * 2);
    unsigned short* qk   = Gch;
    unsigned short* W1T  = (unsigned short*)take((size_t)4 * HH * HH * 2);
    unsigned short* W2T  = (unsigned short*)take((size_t)HH * 4 * HH * 2);
    unsigned short* WlrT = (unsigned short*)take((size_t)512 * HH * 2);
    unsigned short* k2t  = (unsigned short*)take(2048);
    unsigned short* scoresb = (unsigned short*)take((size_t)NN * CC * 2);
    float*          uvec = (float*)take(512 * 4);
    float*          vvec = (float*)take(512 * 4);
    int*            cnt  = (int*)take((size_t)NPAD * 4);
    float*          st1  = (float*)take((size_t)NPAD * 4);
    float*          st2  = (float*)take((size_t)NPAD * 4);
    int*            offb = (int*)take((size_t)(NN + 1) * 4);
    int*            cur  = (int*)take((size_t)NN * 4);
    int*            bsum = (int*)take(256 * 4);
    unsigned int*   pack = (unsigned int*)take((size_t)EE * 4 + 64);

    hipMemsetAsync(cnt, 0, (size_t)3 * NPAD * 4, stream);

    // ---- one prep launch ----
    prep_kernel<<<PB7, 256, 0, stream>>>(
        embedding, scores, W1, W2, Wl, Wr, ln_g, ln_b, bl, br, We, be, emb_table,
        embA, scoresb, W1T, W2T, WlrT, k2t, uvec, vvec);

    // ---- CSR build ----
    hist_kernel<<<(EE + 255) / 256, 256, 0, stream>>>(dst, cnt);
    scan_part<<<NB, 256, 0, stream>>>(cnt, offb, bsum);
    scan_sums<<<1, 256, 0, stream>>>(bsum);
    scan_add<<<NB, 256, 0, stream>>>(offb, bsum, cur);
    fill_kernel<<<(EE + 255) / 256, 256, 0, stream>>>(src, dst, typ, cur, pack);

    // ---- MLP (full-grid): hpre = gelu(X@W1+b1)@W2+b2, stats fused ----
    dim3 g1(4 * HH / 128, NPAD / 128);
    mfma_gemm<1, true, false, false><<<g1, 256, 0, stream>>>(
        embA, W1T, b1, Gch, NN, HH, 4 * HH,
        nullptr, nullptr, nullptr, nullptr, nullptr);
    dim3 g2(HH / 128, NPAD / 128);
    mfma_gemm<0, true, true, false><<<g2, 256, 0, stream>>>(
        Gch, W2T, b2, hpre, NN, 4 * HH, HH,
        st1, st2, nullptr, nullptr, nullptr);

    // ---- q|k1 projection with fused LayerNorm (qk aliases dead Gch) ----
    dim3 gq(512 / 128, NPAD / 128);
    mfma_gemm<0, true, false, true><<<gq, 256, 0, stream>>>(
        hpre, WlrT, vvec, qk, NN, HH, 512,
        nullptr, nullptr, st1, st2, uvec);

    // ---- fused edge phase ----
    fused_edge_kernel<<<(NN + 3) / 4, 256, 0, stream>>>(qk, k2t, offb, pack, scoresb, out);
}